// Round 4
// baseline (7238.568 us; speedup 1.0000x reference)
//
#include <hip/hip_runtime.h>
#include <stdint.h>

#define F_IN 512
#define F_HID 256
#define F_OUT 16
#define K_STEPS 10
#define NN 100000
#define EE 3200000

typedef float f32x4 __attribute__((ext_vector_type(4)));
typedef float f32x2 __attribute__((ext_vector_type(2)));

// ---- in-degree over targets (self loop handled analytically) ----
__global__ __launch_bounds__(256) void count_kernel(const int* __restrict__ ei,
                                                    int* __restrict__ indeg) {
  int i = blockIdx.x * 256 + threadIdx.x;
  if (i < EE) atomicAdd(&indeg[ei[EE + i]], 1);
}

// ---- CSR offsets via atomic bump (bucket order irrelevant) ----
__global__ __launch_bounds__(256) void offsets_kernel(const int* __restrict__ indeg,
                                                      int* __restrict__ node_off,
                                                      int* __restrict__ total) {
  int i = blockIdx.x * 256 + threadIdx.x;
  if (i < NN) node_off[i] = atomicAdd(total, indeg[i]);
}

// ---- CSR fill: sources bucketed by target ----
__global__ __launch_bounds__(256) void fill_kernel(const int* __restrict__ ei,
                                                   const int* __restrict__ node_off,
                                                   int* __restrict__ fillc,
                                                   int* __restrict__ csr_src) {
  int i = blockIdx.x * 256 + threadIdx.x;
  if (i >= EE) return;
  int r = ei[i];
  int c = ei[EE + i];
  int pos = node_off[c] + atomicAdd(&fillc[c], 1);
  csr_src[pos] = r;
}

// ---- w1 [256][512] -> w1T [512][256] ----
__global__ __launch_bounds__(256) void transpose_w1(const float* __restrict__ w1,
                                                    float* __restrict__ w1T) {
  int i = blockIdx.x * 256 + threadIdx.x;
  if (i < F_HID * F_IN) {
    int c = i >> 9, k = i & 511;
    w1T[k * F_HID + c] = w1[i];
  }
}

// ---- fp32 VALU MLP: h = relu(x@w1.T+b1)@w2.T + b2 ; y0 = dinv*h ----
#define XS_STRIDE 516
#define H1_STRIDE 260
__global__ __launch_bounds__(256) void mlp_kernel(const float* __restrict__ x,
                                                  const float* __restrict__ w1T,
                                                  const float* __restrict__ b1,
                                                  const float* __restrict__ w2,
                                                  const float* __restrict__ b2,
                                                  const int* __restrict__ indeg,
                                                  float* __restrict__ h,
                                                  float* __restrict__ y0) {
  __shared__ float xs[32 * XS_STRIDE];   // 66 KB; reused for h1 [32][H1_STRIDE]
  const int tid = threadIdx.x;
  const int m0 = blockIdx.x * 32;

  for (int i = tid * 4; i < 32 * 512; i += 1024) {
    int r = i >> 9, kk = i & 511;
    int row = m0 + r; if (row >= NN) row = NN - 1;
    f32x4 v = *(const f32x4*)(x + (size_t)row * F_IN + kk);
    *(f32x4*)(xs + r * XS_STRIDE + kk) = v;
  }
  __syncthreads();

  const int r  = tid >> 3;          // 0..31
  const int c0 = (tid & 7) * 32;    // 8 threads cover 256 cols
  f32x4 acc[8];
#pragma unroll
  for (int q = 0; q < 8; ++q) acc[q] = *(const f32x4*)(b1 + c0 + q * 4);
  const float* xr = xs + r * XS_STRIDE;
#pragma unroll 2
  for (int k = 0; k < F_IN; ++k) {
    float xv = xr[k];
    const f32x4* wr = (const f32x4*)(w1T + (size_t)k * F_HID + c0);
#pragma unroll
    for (int q = 0; q < 8; ++q) acc[q] += xv * wr[q];
  }
#pragma unroll
  for (int q = 0; q < 8; ++q) {
#pragma unroll
    for (int j = 0; j < 4; ++j) acc[q][j] = acc[q][j] > 0.f ? acc[q][j] : 0.f;
  }
  __syncthreads();                  // everyone done reading xs
  float* h1 = xs;                   // overlay
#pragma unroll
  for (int q = 0; q < 8; ++q) *(f32x4*)(h1 + r * H1_STRIDE + c0 + q * 4) = acc[q];
  __syncthreads();

  // GEMM2: thread -> (row r, outputs o0,o0+1)
  const int o0 = (tid & 7) * 2;
  float a0 = b2[o0], a1 = b2[o0 + 1];
  const float* h1r  = h1 + r * H1_STRIDE;
  const float* w2r0 = w2 + (size_t)o0 * F_HID;
  const float* w2r1 = w2 + (size_t)(o0 + 1) * F_HID;
  for (int nc = 0; nc < F_HID; nc += 4) {
    f32x4 hv = *(const f32x4*)(h1r + nc);
    f32x4 wa = *(const f32x4*)(w2r0 + nc);
    f32x4 wb = *(const f32x4*)(w2r1 + nc);
#pragma unroll
    for (int j = 0; j < 4; ++j) { a0 += hv[j] * wa[j]; a1 += hv[j] * wb[j]; }
  }
  int row = m0 + r;
  if (row < NN) {
    float d  = (float)(indeg[row] + 1);
    float di = rsqrtf(d);
    f32x2 hh = {a0, a1};
    *(f32x2*)(h  + (size_t)row * F_OUT + o0) = hh;
    f32x2 yy = {a0 * di, a1 * di};
    *(f32x2*)(y0 + (size_t)row * F_OUT + o0) = yy;
  }
}

// ---- one PPR step in y-space: y' = 0.9/d * (sum_N y + y_self) + 0.1*dinv*h ----
__global__ __launch_bounds__(256) void ppr_kernel(const int* __restrict__ node_off,
                                                  const int* __restrict__ indeg,
                                                  const int* __restrict__ csr_src,
                                                  const float* __restrict__ yin,
                                                  const float* __restrict__ h,
                                                  float* __restrict__ yout) {
  int t = blockIdx.x * 256 + threadIdx.x;
  int g = t >> 4, f = t & 15;
  if (g >= NN) return;
  int s0 = node_off[g];
  int cnt = indeg[g];
  float acc = yin[(size_t)g * F_OUT + f];   // self loop
  for (int e = 0; e < cnt; ++e) {
    int s = csr_src[s0 + e];
    acc += yin[(size_t)s * F_OUT + f];
  }
  float d = (float)(cnt + 1);
  yout[(size_t)g * F_OUT + f] = 0.9f * acc / d + 0.1f * rsqrtf(d) * h[(size_t)g * F_OUT + f];
}

// ---- output: z = sqrt(d) * y, fp32 ----
__global__ __launch_bounds__(256) void out_kernel(const float* __restrict__ y,
                                                  const int* __restrict__ indeg,
                                                  float* __restrict__ out) {
  int t = blockIdx.x * 256 + threadIdx.x;
  if (t >= NN * F_OUT) return;
  float d = (float)(indeg[t >> 4] + 1);
  out[t] = y[t] * sqrtf(d);
}

extern "C" void kernel_launch(void* const* d_in, const int* in_sizes, int n_in,
                              void* d_out, int out_size, void* d_ws, size_t ws_size,
                              hipStream_t stream) {
  const float* x  = (const float*)d_in[0];
  const float* w1 = (const float*)d_in[1];
  const float* b1 = (const float*)d_in[2];
  const float* w2 = (const float*)d_in[3];
  const float* b2 = (const float*)d_in[4];
  const int*   ei = (const int*)d_in[5];

  char* p = (char*)d_ws;
  auto alloc = [&](size_t bytes) {
    char* r = p;
    p += (bytes + 255) & ~(size_t)255;
    return r;
  };
  float* h   = (float*)alloc((size_t)NN * F_OUT * 4);
  float* ya  = (float*)alloc((size_t)NN * F_OUT * 4);
  float* yb  = (float*)alloc((size_t)NN * F_OUT * 4);
  float* w1T = (float*)alloc((size_t)F_IN * F_HID * 4);
  int* indeg = (int*)alloc(((size_t)2 * NN + 1) * 4);  // indeg | fillc | total
  int* fillc = indeg + NN;
  int* total = fillc + NN;
  int* node_off = (int*)alloc((size_t)NN * 4);
  int* csr_src  = (int*)alloc((size_t)EE * 4);

  hipMemsetAsync(indeg, 0, ((size_t)2 * NN + 1) * 4, stream);

  transpose_w1<<<(F_HID * F_IN + 255) / 256, 256, 0, stream>>>(w1, w1T);
  count_kernel<<<(EE + 255) / 256, 256, 0, stream>>>(ei, indeg);
  offsets_kernel<<<(NN + 255) / 256, 256, 0, stream>>>(indeg, node_off, total);
  fill_kernel<<<(EE + 255) / 256, 256, 0, stream>>>(ei, node_off, fillc, csr_src);
  mlp_kernel<<<(NN + 31) / 32, 256, 0, stream>>>(x, w1T, b1, w2, b2, indeg, h, ya);

  float* yin = ya;
  float* yout = yb;
  for (int k = 0; k < K_STEPS; ++k) {
    ppr_kernel<<<((size_t)NN * 16 + 255) / 256, 256, 0, stream>>>(node_off, indeg, csr_src,
                                                                  yin, h, yout);
    float* tmp = yin; yin = yout; yout = tmp;
  }
  out_kernel<<<((size_t)NN * 16 + 255) / 256, 256, 0, stream>>>(yin, indeg, (float*)d_out);
}

// Round 5
// 1075.781 us; speedup vs baseline: 6.7287x; 6.7287x over previous
//
#include <hip/hip_runtime.h>
#include <stdint.h>

#define F_IN 512
#define F_HID 256
#define F_OUT 16
#define K_STEPS 10
#define NN 100000
#define EE 3200000

typedef float f32x4 __attribute__((ext_vector_type(4)));
typedef float f32x2 __attribute__((ext_vector_type(2)));
typedef short bf16x8 __attribute__((ext_vector_type(8)));

__device__ __forceinline__ unsigned short f2bf(float f) {
  unsigned u = __builtin_bit_cast(unsigned, f);
  u += 0x7FFFu + ((u >> 16) & 1u);   // RNE
  return (unsigned short)(u >> 16);
}
__device__ __forceinline__ float bf2f(unsigned short s) {
  unsigned u = ((unsigned)s) << 16;
  return __builtin_bit_cast(float, u);
}

// ---- in-degree over targets (self loop handled analytically) ----
__global__ __launch_bounds__(256) void count_kernel(const int* __restrict__ ei,
                                                    int* __restrict__ indeg) {
  int i = blockIdx.x * 256 + threadIdx.x;
  if (i < EE) atomicAdd(&indeg[ei[EE + i]], 1);
}

// ---- CSR offsets via atomic bump (bucket order irrelevant) ----
__global__ __launch_bounds__(256) void offsets_kernel(const int* __restrict__ indeg,
                                                      int* __restrict__ node_off,
                                                      int* __restrict__ total) {
  int i = blockIdx.x * 256 + threadIdx.x;
  if (i < NN) node_off[i] = atomicAdd(total, indeg[i]);
}

// ---- CSR fill: sources bucketed by target ----
__global__ __launch_bounds__(256) void fill_kernel(const int* __restrict__ ei,
                                                   const int* __restrict__ node_off,
                                                   int* __restrict__ fillc,
                                                   int* __restrict__ csr_src) {
  int i = blockIdx.x * 256 + threadIdx.x;
  if (i >= EE) return;
  int r = ei[i];
  int c = ei[EE + i];
  int pos = node_off[c] + atomicAdd(&fillc[c], 1);
  csr_src[pos] = r;
}

// ---- w1 -> bf16 (layout kept: [256 hidden][512 k], k contiguous = B^T) ----
__global__ __launch_bounds__(256) void convert_w1_kernel(const float* __restrict__ w1,
                                                         unsigned short* __restrict__ w1b) {
  int i = blockIdx.x * 256 + threadIdx.x;
  if (i < F_HID * F_IN) w1b[i] = f2bf(w1[i]);
}

// ---- MFMA MLP: h = relu(x@w1.T+b1)@w2.T + b2 ; y0 = dinv*h ----
// 256 thr = 4 waves; wave w -> 16 rows; 64 rows/block.
// GEMM1: mfma_f32_16x16x32_bf16, 16 N-frags x 16 k-steps per wave.
__global__ __launch_bounds__(256) void mlp_kernel(const float* __restrict__ x,
                                                  const unsigned short* __restrict__ w1b,
                                                  const float* __restrict__ b1,
                                                  const float* __restrict__ w2,
                                                  const float* __restrict__ b2,
                                                  const int* __restrict__ indeg,
                                                  float* __restrict__ h,
                                                  float* __restrict__ y0) {
  __shared__ unsigned short w2s[16][264];      // bf16 w2, padded
  __shared__ unsigned short h1s[4][16][264];   // per-wave relu(h1) strip, bf16

  const int tid = threadIdx.x;
  for (int i = tid; i < F_OUT * F_HID; i += 256) w2s[i >> 8][i & 255] = f2bf(w2[i]);
  __syncthreads();

  const int wave = tid >> 6, l = tid & 63;
  const int lr = l & 15, lk = l >> 4;          // lane row/col idx, k-group
  const int m0 = blockIdx.x * 64 + wave * 16;
  const int row = m0 + lr;
  const int rowc = row < NN ? row : (NN - 1);
  const float* xp = x + (size_t)rowc * F_IN + lk * 8;

  f32x4 acc[16];
#pragma unroll
  for (int t = 0; t < 16; ++t) acc[t] = (f32x4){0.f, 0.f, 0.f, 0.f};

  const unsigned short* wp0 = w1b + (size_t)lr * F_IN + lk * 8;
  for (int ki = 0; ki < F_IN / 32; ++ki) {
    // A frag: A[row=m0+lr][k = ki*32 + lk*8 + j], 8 contiguous k
    f32x4 a0 = *(const f32x4*)(xp + ki * 32);
    f32x4 a1 = *(const f32x4*)(xp + ki * 32 + 4);
    bf16x8 af;
#pragma unroll
    for (int j = 0; j < 4; ++j) { af[j] = (short)f2bf(a0[j]); af[j + 4] = (short)f2bf(a1[j]); }
    const unsigned short* wp = wp0 + ki * 32;
#pragma unroll
    for (int nt = 0; nt < 16; ++nt) {
      // B frag: B[col = nt*16+lr][same k] (w1 row-major = B^T)
      bf16x8 bf = *(const bf16x8*)(wp + nt * 16 * F_IN);
      acc[nt] = __builtin_amdgcn_mfma_f32_16x16x32_bf16(af, bf, acc[nt], 0, 0, 0);
    }
  }

  // epilogue 1: +b1, relu, bf16 -> LDS. D: col=lane&15 (N), row=(lane>>4)*4+reg (M)
#pragma unroll
  for (int nt = 0; nt < 16; ++nt) {
#pragma unroll
    for (int r = 0; r < 4; ++r) {
      int rr = lk * 4 + r, cc = nt * 16 + lr;
      float v = acc[nt][r] + b1[cc];
      v = v > 0.f ? v : 0.f;
      h1s[wave][rr][cc] = f2bf(v);
    }
  }
  __syncthreads();

  // epilogue 2: h2[m][o] = sum_n h1[m][n]*w2[o][n] + b2[o]; lane: m=lr, o=lk*4+j
  float hacc[4];
#pragma unroll
  for (int j = 0; j < 4; ++j) hacc[j] = b2[lk * 4 + j];
  for (int nc = 0; nc < F_HID; nc += 8) {
    bf16x8 hv = *(const bf16x8*)&h1s[wave][lr][nc];
    float hf[8];
#pragma unroll
    for (int q = 0; q < 8; ++q) hf[q] = bf2f((unsigned short)hv[q]);
#pragma unroll
    for (int j = 0; j < 4; ++j) {
      bf16x8 wv = *(const bf16x8*)&w2s[lk * 4 + j][nc];
#pragma unroll
      for (int q = 0; q < 8; ++q) hacc[j] += hf[q] * bf2f((unsigned short)wv[q]);
    }
  }
  if (row < NN) {
    float d  = (float)(indeg[row] + 1);
    float di = rsqrtf(d);
    f32x4 hh = {hacc[0], hacc[1], hacc[2], hacc[3]};
    *(f32x4*)(h + (size_t)row * F_OUT + lk * 4) = hh;
    f32x4 yy = {hacc[0] * di, hacc[1] * di, hacc[2] * di, hacc[3] * di};
    *(f32x4*)(y0 + (size_t)row * F_OUT + lk * 4) = yy;
  }
}

// ---- one PPR step in y-space: y' = 0.9/d * (sum_N y + y_self) + 0.1*dinv*h ----
// 16 lanes per node; 16-edge chunks: coalesced csr load + shfl broadcast +
// 16 independent 64B y-row gathers in flight.
__global__ __launch_bounds__(256) void ppr_kernel(const int* __restrict__ node_off,
                                                  const int* __restrict__ indeg,
                                                  const int* __restrict__ csr_src,
                                                  const float* __restrict__ yin,
                                                  const float* __restrict__ h,
                                                  float* __restrict__ yout) {
  int t = blockIdx.x * 256 + threadIdx.x;
  int g = t >> 4, f = t & 15;
  if (g >= NN) return;
  const int gb = threadIdx.x & 48;          // 16-lane group base within wave
  int s0 = node_off[g];
  int cnt = indeg[g];
  float acc = yin[(size_t)g * F_OUT + f];   // self loop
  int base = 0;
  for (; base + 16 <= cnt; base += 16) {
    int sidx = csr_src[s0 + base + f];      // 16 lanes -> 16 edges, coalesced
#pragma unroll
    for (int j = 0; j < 16; ++j) {
      int s = __shfl(sidx, gb + j, 64);
      acc += yin[(size_t)s * F_OUT + f];
    }
  }
  int rem = cnt - base;
  if (rem > 0) {
    int sidx = csr_src[s0 + base + (f < rem ? f : 0)];
    for (int j = 0; j < rem; ++j) {
      int s = __shfl(sidx, gb + j, 64);
      acc += yin[(size_t)s * F_OUT + f];
    }
  }
  float d = (float)(cnt + 1);
  yout[(size_t)g * F_OUT + f] = 0.9f * acc / d + 0.1f * rsqrtf(d) * h[(size_t)g * F_OUT + f];
}

// ---- output: z = sqrt(d) * y, fp32 ----
__global__ __launch_bounds__(256) void out_kernel(const float* __restrict__ y,
                                                  const int* __restrict__ indeg,
                                                  float* __restrict__ out) {
  int t = blockIdx.x * 256 + threadIdx.x;
  if (t >= NN * F_OUT) return;
  float d = (float)(indeg[t >> 4] + 1);
  out[t] = y[t] * sqrtf(d);
}

extern "C" void kernel_launch(void* const* d_in, const int* in_sizes, int n_in,
                              void* d_out, int out_size, void* d_ws, size_t ws_size,
                              hipStream_t stream) {
  const float* x  = (const float*)d_in[0];
  const float* w1 = (const float*)d_in[1];
  const float* b1 = (const float*)d_in[2];
  const float* w2 = (const float*)d_in[3];
  const float* b2 = (const float*)d_in[4];
  const int*   ei = (const int*)d_in[5];

  char* p = (char*)d_ws;
  auto alloc = [&](size_t bytes) {
    char* r = p;
    p += (bytes + 255) & ~(size_t)255;
    return r;
  };
  float* h   = (float*)alloc((size_t)NN * F_OUT * 4);
  float* ya  = (float*)alloc((size_t)NN * F_OUT * 4);
  float* yb  = (float*)alloc((size_t)NN * F_OUT * 4);
  unsigned short* w1b = (unsigned short*)alloc((size_t)F_HID * F_IN * 2);
  int* indeg = (int*)alloc(((size_t)2 * NN + 1) * 4);  // indeg | fillc | total
  int* fillc = indeg + NN;
  int* total = fillc + NN;
  int* node_off = (int*)alloc((size_t)NN * 4);
  int* csr_src  = (int*)alloc((size_t)EE * 4);

  hipMemsetAsync(indeg, 0, ((size_t)2 * NN + 1) * 4, stream);

  convert_w1_kernel<<<(F_HID * F_IN + 255) / 256, 256, 0, stream>>>(w1, w1b);
  count_kernel<<<(EE + 255) / 256, 256, 0, stream>>>(ei, indeg);
  offsets_kernel<<<(NN + 255) / 256, 256, 0, stream>>>(indeg, node_off, total);
  fill_kernel<<<(EE + 255) / 256, 256, 0, stream>>>(ei, node_off, fillc, csr_src);
  mlp_kernel<<<(NN + 63) / 64, 256, 0, stream>>>(x, w1b, b1, w2, b2, indeg, h, ya);

  float* yin = ya;
  float* yout = yb;
  for (int k = 0; k < K_STEPS; ++k) {
    ppr_kernel<<<((size_t)NN * 16 + 255) / 256, 256, 0, stream>>>(node_off, indeg, csr_src,
                                                                  yin, h, yout);
    float* tmp = yin; yin = yout; yout = tmp;
  }
  out_kernel<<<((size_t)NN * 16 + 255) / 256, 256, 0, stream>>>(yin, indeg, (float*)d_out);
}